// Round 11
// baseline (118.364 us; speedup 1.0000x reference)
//
#include <hip/hip_runtime.h>
#include <hip/hip_bf16.h>
#include <stdint.h>

#define N_PTS   4096
#define M_CODES 4096
#define ZDIM    1024
#define KG      (ZDIM / 8)          // 128 k-groups of 8 elements
// Tiled bf16 layout: elem (r,k) at seg(rb)*16384 + kg*128 + r16*8 + ke
//   rb=r>>4, r16=r&15, kg=k>>3, ke=k&7. Chunk (rb,kg) = 16 rows x 8 k = 256 B.

typedef __attribute__((ext_vector_type(8))) short bf16x8;
typedef __attribute__((ext_vector_type(4))) float f32x4;

__device__ __forceinline__ unsigned short f2bf(float f) {
    __hip_bfloat16 h = __float2bfloat16(f);
    return *reinterpret_cast<unsigned short*>(&h);
}
__device__ __forceinline__ unsigned enc_f32(float f) {
    unsigned u = __float_as_uint(f);
    return (u & 0x80000000u) ? ~u : (u | 0x80000000u);
}
__device__ __forceinline__ float dec_f32(unsigned e) {
    unsigned u = (e & 0x80000000u) ? (e ^ 0x80000000u) : ~u;
    return __uint_as_float(u);
}

// ---------------------------------------------------------------------------
// prep: fp32 -> bf16 + TILED layout + row sum-of-squares.
// R10 lesson: __shfl_xor = ds_swizzle = LDS pipe; 96 shfl/thread was ~25 us.
// New reduction: phase 2 accumulates each thread's 64 elements of row t&15
// in fp32 from the bf16 values (consistent with the bf16 GEMM), then just
// 2 shfl + one small LDS combine. zsq/esq = ||bf16(x)||^2 (error ~0.25,
// threshold 35.5).
// ---------------------------------------------------------------------------
#define PREP_PITCH 1032   // ushorts per LDS row: 1024 + 8 pad (16 B-aligned)
__global__ __launch_bounds__(256) void prep_kernel(
    const float* __restrict__ z, const float* __restrict__ e,
    unsigned short* __restrict__ zb, unsigned short* __restrict__ eb,
    float* __restrict__ zsq, float* __restrict__ esq,
    unsigned* __restrict__ min_enc) {
    __shared__ unsigned short tile[16 * PREP_PITCH];  // ~33 KB
    __shared__ float redbuf[4 * 16];

    const int t = threadIdx.x;
    const int b = blockIdx.x;
    if (b < 16) min_enc[b * 256 + t] = 0xFFFFFFFFu;

    const bool is_z = b < 256;
    const int rb = b & 255;
    const float* src = (is_z ? z : e) + (size_t)rb * 16 * ZDIM;
    unsigned short* dst = (is_z ? zb : eb) + (size_t)rb * 16384;  // 32 KB seg
    const int w = t >> 6, lane = t & 63;

    // Phase 1: convert only, no reduction.
    #pragma unroll
    for (int it = 0; it < 16; it++) {
        float4 v = reinterpret_cast<const float4*>(src + (size_t)it * ZDIM)[t];
        ushort4 o;
        o.x = f2bf(v.x); o.y = f2bf(v.y); o.z = f2bf(v.z); o.w = f2bf(v.w);
        *reinterpret_cast<ushort4*>(&tile[it * PREP_PITCH + t * 4]) = o;
    }
    __syncthreads();

    // Phase 2: transpose-store + per-thread fp32 accumulation of row t&15.
    float s = 0.f;
    #pragma unroll
    for (int it2 = 0; it2 < 8; it2++) {
        const int c = it2 * 256 + t;          // 0..2047
        const int kg = c >> 4, r16 = c & 15;  // r16 == t&15 (thread-constant)
        bf16x8 val = *reinterpret_cast<const bf16x8*>(
            &tile[r16 * PREP_PITCH + kg * 8]);
        *reinterpret_cast<bf16x8*>(&dst[(size_t)c * 8]) = val;
        #pragma unroll
        for (int j = 0; j < 8; j++) {
            float f = __uint_as_float(((unsigned)(unsigned short)val[j]) << 16);
            s = fmaf(f, f, s);
        }
    }
    // lanes {l, l^16, l^32, l^48} share the same row: 2 shfl total.
    s += __shfl_xor(s, 16, 64);
    s += __shfl_xor(s, 32, 64);
    if (lane < 16) redbuf[w * 16 + lane] = s;
    __syncthreads();
    if (t < 16) {
        float sq = redbuf[t] + redbuf[16 + t] + redbuf[32 + t] + redbuf[48 + t];
        const int row = rb * 16 + t;
        if (is_z) zsq[row] = sq; else esq[row] = sq;
    }
}

// ---------------------------------------------------------------------------
// gemm_min: BARRIER-FREE, LDS-FREE K-loop. Both A and B fragments are
// contiguous, perfectly-coalesced 1 KB lane-linear wave reads straight from
// the tiled global layout (addr = seg*16384 + kg*128 + lane*8 — identical
// fragment math to the R8-proven LDS version). 32 slices x (8 loads +
// 16 MFMA), no __syncthreads in the loop, latency hidden by 16 waves/CU.
// LDS only for the epilogue (zsq_s + colmin). grid (32,32), 256 thr,
// __launch_bounds__(256,4) pins VGPR<=128 -> 4 blocks/CU.
// ---------------------------------------------------------------------------
__global__ __launch_bounds__(256, 4) void gemm_min_kernel(
    const unsigned short* __restrict__ zb, const unsigned short* __restrict__ eb,
    const float* __restrict__ zsq, unsigned* __restrict__ min_enc) {
    __shared__ float zsq_s[128];
    __shared__ float colmin[2][128];

    const int t = threadIdx.x;        // 0..255
    const int bx = blockIdx.x;        // code (col) block
    const int by = blockIdx.y;        // point (row) block
    const int lane = t & 63;
    const int w = t >> 6;             // 0..3
    const int wm = w >> 1, wn = w & 1;
    const int lrow = lane & 15;
    const int q = lane >> 4;

    if (t < 128) zsq_s[t] = zsq[by * 128 + t];

    f32x4 acc[4][4];
    #pragma unroll
    for (int i = 0; i < 4; i++)
        #pragma unroll
        for (int j = 0; j < 4; j++) acc[i][j] = (f32x4){0.f, 0.f, 0.f, 0.f};

    // Fragment bases: lane addr = q*128 + lrow*8 = lane*8 (lane-linear 1 KB).
    const unsigned short* a_base =
        zb + (size_t)(by * 8 + wm * 4) * 16384 + lane * 8;
    const unsigned short* b_base =
        eb + (size_t)(bx * 8 + wn * 4) * 16384 + lane * 8;

    for (int kg0 = 0; kg0 < KG; kg0 += 8) {   // 16 stages, 2 slices each
        #pragma unroll
        for (int s = 0; s < 2; s++) {
            const int off = kg0 * 128 + s * 512;
            bf16x8 a[4], bb[4];
            #pragma unroll
            for (int am = 0; am < 4; am++)
                a[am] = *(const bf16x8*)(a_base + (size_t)am * 16384 + off);
            #pragma unroll
            for (int an = 0; an < 4; an++)
                bb[an] = *(const bf16x8*)(b_base + (size_t)an * 16384 + off);
            #pragma unroll
            for (int am = 0; am < 4; am++)
                #pragma unroll
                for (int an = 0; an < 4; an++)
                    acc[am][an] = __builtin_amdgcn_mfma_f32_16x16x32_bf16(
                        a[am], bb[an], acc[am][an], 0, 0, 0);
        }
    }

    __syncthreads();  // zsq_s visible (written at kernel start)

    // Epilogue (R5/R6-proven). C/D layout: row = q*4+r, col = lrow.
    #pragma unroll
    for (int an = 0; an < 4; an++) {
        float v = 3.4e38f;
        #pragma unroll
        for (int am = 0; am < 4; am++) {
            const int rbase = wm * 64 + am * 16 + q * 4;
            f32x4 c = acc[am][an];
            v = fminf(v, zsq_s[rbase + 0] - 2.f * c[0]);
            v = fminf(v, zsq_s[rbase + 1] - 2.f * c[1]);
            v = fminf(v, zsq_s[rbase + 2] - 2.f * c[2]);
            v = fminf(v, zsq_s[rbase + 3] - 2.f * c[3]);
        }
        v = fminf(v, __shfl_xor(v, 16, 64));
        v = fminf(v, __shfl_xor(v, 32, 64));
        if (q == 0) colmin[wm][wn * 64 + an * 16 + lrow] = v;
    }
    __syncthreads();
    if (t < 128) {
        const float m = fminf(colmin[0][t], colmin[1][t]);
        atomicMin(&min_enc[bx * 128 + t], enc_f32(m));
    }
}

// ---------------------------------------------------------------------------
// finalize: mean_j (dec(min_enc[j]) + esq[j]) -> single fp32 scalar.
// ---------------------------------------------------------------------------
__global__ __launch_bounds__(256) void finalize_kernel(
    const unsigned* __restrict__ min_enc, const float* __restrict__ esq,
    float* __restrict__ out) {
    const int t = threadIdx.x;
    float s = 0.f;
    #pragma unroll
    for (int i = 0; i < M_CODES / 256; i++) {
        const int j = i * 256 + t;
        s += dec_f32(min_enc[j]) + esq[j];
    }
    #pragma unroll
    for (int off = 1; off < 64; off <<= 1) s += __shfl_xor(s, off, 64);
    __shared__ float red[4];
    if ((t & 63) == 0) red[t >> 6] = s;
    __syncthreads();
    if (t == 0) out[0] = (red[0] + red[1] + red[2] + red[3]) * (1.f / M_CODES);
}

extern "C" void kernel_launch(void* const* d_in, const int* in_sizes, int n_in,
                              void* d_out, int out_size, void* d_ws, size_t ws_size,
                              hipStream_t stream) {
    (void)in_sizes; (void)n_in; (void)out_size; (void)ws_size;
    const float* z = (const float*)d_in[0];
    const float* e = (const float*)d_in[1];
    char* ws = (char*)d_ws;
    unsigned short* zb = (unsigned short*)ws;                            // 8 MB
    unsigned short* eb = (unsigned short*)(ws + ((size_t)8 << 20));      // 8 MB
    float* zsq = (float*)(ws + ((size_t)16 << 20));                      // 16 KB
    float* esq = (float*)(ws + ((size_t)16 << 20) + 16384);              // 16 KB
    unsigned* min_enc = (unsigned*)(ws + ((size_t)16 << 20) + 32768);    // 16 KB

    prep_kernel<<<dim3(512), dim3(256), 0, stream>>>(
        z, e, zb, eb, zsq, esq, min_enc);
    gemm_min_kernel<<<dim3(32, 32), dim3(256), 0, stream>>>(
        zb, eb, zsq, min_enc);
    finalize_kernel<<<dim3(1), dim3(256), 0, stream>>>(min_enc, esq, (float*)d_out);
}

// Round 12
// 112.515 us; speedup vs baseline: 1.0520x; 1.0520x over previous
//
#include <hip/hip_runtime.h>
#include <hip/hip_bf16.h>
#include <stdint.h>

#define N_PTS   4096
#define M_CODES 4096
#define ZDIM    1024
#define KG      (ZDIM / 8)          // 128 k-groups of 8 elements
// Tiled bf16 layout: elem (r,k) at seg(rb)*16384 + kg*128 + r16*8 + ke
//   rb=r>>4, r16=r&15, kg=k>>3, ke=k&7. Chunk (rb,kg) = 16 rows x 8 k = 256 B.

typedef __attribute__((ext_vector_type(8))) short bf16x8;
typedef __attribute__((ext_vector_type(4))) float f32x4;

__device__ __forceinline__ unsigned short f2bf(float f) {
    __hip_bfloat16 h = __float2bfloat16(f);
    return *reinterpret_cast<unsigned short*>(&h);
}
__device__ __forceinline__ unsigned enc_f32(float f) {
    unsigned u = __float_as_uint(f);
    return (u & 0x80000000u) ? ~u : (u | 0x80000000u);
}
__device__ __forceinline__ float dec_f32(unsigned e) {
    unsigned u = (e & 0x80000000u) ? (e ^ 0x80000000u) : ~u;
    return __uint_as_float(u);
}

// ---------------------------------------------------------------------------
// prep: fp32 -> bf16 + TILED layout + row sum-of-squares (R11, unchanged —
// measured equal to R8's; non-gemm time is harness fixed cost, not prep).
// ---------------------------------------------------------------------------
#define PREP_PITCH 1032   // ushorts per LDS row: 1024 + 8 pad (16 B-aligned)
__global__ __launch_bounds__(256) void prep_kernel(
    const float* __restrict__ z, const float* __restrict__ e,
    unsigned short* __restrict__ zb, unsigned short* __restrict__ eb,
    float* __restrict__ zsq, float* __restrict__ esq,
    unsigned* __restrict__ min_enc) {
    __shared__ unsigned short tile[16 * PREP_PITCH];  // ~33 KB
    __shared__ float redbuf[4 * 16];

    const int t = threadIdx.x;
    const int b = blockIdx.x;
    if (b < 16) min_enc[b * 256 + t] = 0xFFFFFFFFu;

    const bool is_z = b < 256;
    const int rb = b & 255;
    const float* src = (is_z ? z : e) + (size_t)rb * 16 * ZDIM;
    unsigned short* dst = (is_z ? zb : eb) + (size_t)rb * 16384;  // 32 KB seg
    const int w = t >> 6, lane = t & 63;

    #pragma unroll
    for (int it = 0; it < 16; it++) {
        float4 v = reinterpret_cast<const float4*>(src + (size_t)it * ZDIM)[t];
        ushort4 o;
        o.x = f2bf(v.x); o.y = f2bf(v.y); o.z = f2bf(v.z); o.w = f2bf(v.w);
        *reinterpret_cast<ushort4*>(&tile[it * PREP_PITCH + t * 4]) = o;
    }
    __syncthreads();

    float s = 0.f;
    #pragma unroll
    for (int it2 = 0; it2 < 8; it2++) {
        const int c = it2 * 256 + t;          // 0..2047
        const int kg = c >> 4, r16 = c & 15;  // r16 == t&15 (thread-constant)
        bf16x8 val = *reinterpret_cast<const bf16x8*>(
            &tile[r16 * PREP_PITCH + kg * 8]);
        *reinterpret_cast<bf16x8*>(&dst[(size_t)c * 8]) = val;
        #pragma unroll
        for (int j = 0; j < 8; j++) {
            float f = __uint_as_float(((unsigned)(unsigned short)val[j]) << 16);
            s = fmaf(f, f, s);
        }
    }
    s += __shfl_xor(s, 16, 64);
    s += __shfl_xor(s, 32, 64);
    if (lane < 16) redbuf[w * 16 + lane] = s;
    __syncthreads();
    if (t < 16) {
        float sq = redbuf[t] + redbuf[16 + t] + redbuf[32 + t] + redbuf[48 + t];
        const int row = rb * 16 + t;
        if (is_z) zsq[row] = sq; else esq[row] = sq;
    }
}

// ---------------------------------------------------------------------------
// gemm_min: single-barrier DOUBLE-BUFFERED pipeline.
//   per stage (K=64): barrier -> issue DMA(st+1 -> buf^1) -> compute(st,buf).
//   The barrier's implicit vmcnt(0) drain lands a full compute-stage after
//   the DMA was issued (true overlap); buffer-reuse safety = the barrier's
//   wave-convergence guarantee. 16 barriers total (R10 had 32, zero overlap).
// A through LDS (shared across wn waves), B direct from global (R10-proven:
// tiled layout makes each fragment a contiguous lane-linear 1 KB wave read).
// 256 thr = 4 waves (2x2 of 64x64), grid (32,32), 4 blocks/CU.
// ---------------------------------------------------------------------------
__global__ __launch_bounds__(256, 4) void gemm_min_kernel(
    const unsigned short* __restrict__ zb, const unsigned short* __restrict__ eb,
    const float* __restrict__ zsq, unsigned* __restrict__ min_enc) {
    __shared__ __align__(16) unsigned short As[16384];  // 2 x 16 KB
    __shared__ float zsq_s[128];
    __shared__ float colmin[2][128];

    const int t = threadIdx.x;        // 0..255
    const int bx = blockIdx.x;        // code (col) block
    const int by = blockIdx.y;        // point (row) block
    const int lane = t & 63;
    const int w = t >> 6;             // 0..3
    const int wm = w >> 1, wn = w & 1;
    const int lrow = lane & 15;
    const int q = lane >> 4;

    if (t < 128) zsq_s[t] = zsq[by * 128 + t];

    f32x4 acc[4][4];
    #pragma unroll
    for (int i = 0; i < 4; i++)
        #pragma unroll
        for (int j = 0; j < 4; j++) acc[i][j] = (f32x4){0.f, 0.f, 0.f, 0.f};

    // A staging geometry (R10-proven): instr j covers 4 KB = 2 segs' 2 KB
    // runs; global addr is lane-linear 16 B within each wave.
    const int seg_half = t >> 7;            // 0..1
    const int inner = (t & 127) * 8;        // element offset in 2 KB run
    const int lds_w = w * 512;              // wave-uniform (elements)
    const size_t a_seg0 = (size_t)(by * 8) * 16384;

    // B fragment base: lane addr = lane*8 (lane-linear 1 KB per fragment).
    const unsigned short* b_base =
        eb + (size_t)(bx * 8 + wn * 4) * 16384 + lane * 8;

    // 16 stages of K=64; stage st covers seg elements [st*1024, st*1024+1024).
#define DMA_STAGE(st_)                                                        \
    {                                                                         \
        const int buf_ = ((st_) & 1) * 8192;                                  \
        const int koff_ = (st_) * 1024;                                       \
        _Pragma("unroll")                                                     \
        for (int j = 0; j < 4; j++) {                                         \
            const unsigned short* ga = zb + a_seg0 +                          \
                (size_t)(j * 2 + seg_half) * 16384 + koff_ + inner;           \
            __builtin_amdgcn_global_load_lds(                                 \
                (const __attribute__((address_space(1))) void*)ga,            \
                (__attribute__((address_space(3))) void*)(As + buf_ +         \
                    j * 2048 + lds_w), 16, 0, 0);                             \
        }                                                                     \
    }

    DMA_STAGE(0);
    for (int st = 0; st < 16; st++) {
        __syncthreads();                 // drains DMA(st); compute(st-1) done
        if (st < 15) DMA_STAGE(st + 1);  // overlaps with compute(st)
        const int buf = (st & 1) * 8192;
        const int koff = st * 1024;
        #pragma unroll
        for (int s = 0; s < 2; s++) {    // two K=32 slices
            bf16x8 a[4], bb[4];
            #pragma unroll
            for (int an = 0; an < 4; an++)
                bb[an] = *(const bf16x8*)(b_base + (size_t)an * 16384 +
                                          koff + s * 512);
            #pragma unroll
            for (int am = 0; am < 4; am++)
                a[am] = *(const bf16x8*)(As + buf + (wm * 4 + am) * 1024 +
                                         s * 512 + lane * 8);
            #pragma unroll
            for (int am = 0; am < 4; am++)
                #pragma unroll
                for (int an = 0; an < 4; an++)
                    acc[am][an] = __builtin_amdgcn_mfma_f32_16x16x32_bf16(
                        a[am], bb[an], acc[am][an], 0, 0, 0);
        }
    }
#undef DMA_STAGE

    __syncthreads();

    // Epilogue (R5/R6-proven). C/D layout: row = q*4+r, col = lrow.
    #pragma unroll
    for (int an = 0; an < 4; an++) {
        float v = 3.4e38f;
        #pragma unroll
        for (int am = 0; am < 4; am++) {
            const int rbase = wm * 64 + am * 16 + q * 4;
            f32x4 c = acc[am][an];
            v = fminf(v, zsq_s[rbase + 0] - 2.f * c[0]);
            v = fminf(v, zsq_s[rbase + 1] - 2.f * c[1]);
            v = fminf(v, zsq_s[rbase + 2] - 2.f * c[2]);
            v = fminf(v, zsq_s[rbase + 3] - 2.f * c[3]);
        }
        v = fminf(v, __shfl_xor(v, 16, 64));
        v = fminf(v, __shfl_xor(v, 32, 64));
        if (q == 0) colmin[wm][wn * 64 + an * 16 + lrow] = v;
    }
    __syncthreads();
    if (t < 128) {
        const float m = fminf(colmin[0][t], colmin[1][t]);
        atomicMin(&min_enc[bx * 128 + t], enc_f32(m));
    }
}

// ---------------------------------------------------------------------------
// finalize: mean_j (dec(min_enc[j]) + esq[j]) -> single fp32 scalar.
// ---------------------------------------------------------------------------
__global__ __launch_bounds__(256) void finalize_kernel(
    const unsigned* __restrict__ min_enc, const float* __restrict__ esq,
    float* __restrict__ out) {
    const int t = threadIdx.x;
    float s = 0.f;
    #pragma unroll
    for (int i = 0; i < M_CODES / 256; i++) {
        const int j = i * 256 + t;
        s += dec_f32(min_enc[j]) + esq[j];
    }
    #pragma unroll
    for (int off = 1; off < 64; off <<= 1) s += __shfl_xor(s, off, 64);
    __shared__ float red[4];
    if ((t & 63) == 0) red[t >> 6] = s;
    __syncthreads();
    if (t == 0) out[0] = (red[0] + red[1] + red[2] + red[3]) * (1.f / M_CODES);
}

extern "C" void kernel_launch(void* const* d_in, const int* in_sizes, int n_in,
                              void* d_out, int out_size, void* d_ws, size_t ws_size,
                              hipStream_t stream) {
    (void)in_sizes; (void)n_in; (void)out_size; (void)ws_size;
    const float* z = (const float*)d_in[0];
    const float* e = (const float*)d_in[1];
    char* ws = (char*)d_ws;
    unsigned short* zb = (unsigned short*)ws;                            // 8 MB
    unsigned short* eb = (unsigned short*)(ws + ((size_t)8 << 20));      // 8 MB
    float* zsq = (float*)(ws + ((size_t)16 << 20));                      // 16 KB
    float* esq = (float*)(ws + ((size_t)16 << 20) + 16384);              // 16 KB
    unsigned* min_enc = (unsigned*)(ws + ((size_t)16 << 20) + 32768);    // 16 KB

    prep_kernel<<<dim3(512), dim3(256), 0, stream>>>(
        z, e, zb, eb, zsq, esq, min_enc);
    gemm_min_kernel<<<dim3(32, 32), dim3(256), 0, stream>>>(
        zb, eb, zsq, min_enc);
    finalize_kernel<<<dim3(1), dim3(256), 0, stream>>>(min_enc, esq, (float*)d_out);
}